// Round 2
// baseline (329.875 us; speedup 1.0000x reference)
//
#include <hip/hip_runtime.h>
#include <stdint.h>
#include <math.h>

// Sizes
#define NN 512   // N_NODES
#define HID 64
#define LAT 256
#define TS 10
#define BAT 64

#define DEVFN static __device__ __forceinline__

DEVFN uint32_t rotl32(uint32_t v, int d) { return (v << d) | (v >> (32 - d)); }

// Threefry-2x32, 20 rounds (JAX threefry2x32_p). key=(k0,k1), count=(x0,x1).
DEVFN void threefry2x32(uint32_t k0, uint32_t k1, uint32_t x0, uint32_t x1,
                        uint32_t& o0, uint32_t& o1) {
  uint32_t ks0 = k0, ks1 = k1, ks2 = k0 ^ k1 ^ 0x1BD11BDAu;
  x0 += ks0; x1 += ks1;
  x0 += x1; x1 = rotl32(x1, 13); x1 ^= x0;
  x0 += x1; x1 = rotl32(x1, 15); x1 ^= x0;
  x0 += x1; x1 = rotl32(x1, 26); x1 ^= x0;
  x0 += x1; x1 = rotl32(x1, 6);  x1 ^= x0;
  x0 += ks1; x1 += ks2 + 1u;
  x0 += x1; x1 = rotl32(x1, 17); x1 ^= x0;
  x0 += x1; x1 = rotl32(x1, 29); x1 ^= x0;
  x0 += x1; x1 = rotl32(x1, 16); x1 ^= x0;
  x0 += x1; x1 = rotl32(x1, 24); x1 ^= x0;
  x0 += ks2; x1 += ks0 + 2u;
  x0 += x1; x1 = rotl32(x1, 13); x1 ^= x0;
  x0 += x1; x1 = rotl32(x1, 15); x1 ^= x0;
  x0 += x1; x1 = rotl32(x1, 26); x1 ^= x0;
  x0 += x1; x1 = rotl32(x1, 6);  x1 ^= x0;
  x0 += ks0; x1 += ks1 + 3u;
  x0 += x1; x1 = rotl32(x1, 17); x1 ^= x0;
  x0 += x1; x1 = rotl32(x1, 29); x1 ^= x0;
  x0 += x1; x1 = rotl32(x1, 16); x1 ^= x0;
  x0 += x1; x1 = rotl32(x1, 24); x1 ^= x0;
  x0 += ks1; x1 += ks2 + 4u;
  x0 += x1; x1 = rotl32(x1, 13); x1 ^= x0;
  x0 += x1; x1 = rotl32(x1, 15); x1 ^= x0;
  x0 += x1; x1 = rotl32(x1, 26); x1 ^= x0;
  x0 += x1; x1 = rotl32(x1, 6);  x1 ^= x0;
  x0 += ks2; x1 += ks0 + 5u;
  o0 = x0; o1 = x1;
}

DEVFN float sigmoidf_(float x) { return 1.0f / (1.0f + expf(-x)); }

// JAX gumbel from 32 random bits: uniform in [tiny, 1), g = -log(-log(u))
DEVFN float gumbel_bits(uint32_t bits) {
  const float tiny = 1.17549435e-38f;
  float f = __uint_as_float((bits >> 9) | 0x3F800000u) - 1.0f;
  float u = f * (1.0f - tiny) + tiny;
  u = fmaxf(tiny, u);
  return -logf(-logf(u));
}

// 256-thread block reduction (4 waves of 64)
DEVFN float block_red256(float v, float* red, bool ismax) {
  #pragma unroll
  for (int o = 32; o > 0; o >>= 1) {
    float w = __shfl_down(v, o, 64);
    v = ismax ? fmaxf(v, w) : v + w;
  }
  if ((threadIdx.x & 63) == 0) red[threadIdx.x >> 6] = v;
  __syncthreads();
  float r = ismax ? fmaxf(fmaxf(red[0], red[1]), fmaxf(red[2], red[3]))
                  : ((red[0] + red[1]) + (red[2] + red[3]));
  __syncthreads();
  return r;
}

// ---------------- Transformer encoder (whole thing, one block per batch b) -----
__global__ __launch_bounds__(256) void enc_kernel(
    const float* __restrict__ X, const float* __restrict__ wp1, const float* __restrict__ bp1,
    const float* __restrict__ in_w, const float* __restrict__ in_b,
    const float* __restrict__ out_w, const float* __restrict__ out_b,
    const float* __restrict__ l1_w, const float* __restrict__ l1_b,
    const float* __restrict__ l2_w, const float* __restrict__ l2_b,
    const float* __restrict__ g1, const float* __restrict__ b1,
    const float* __restrict__ g2, const float* __restrict__ b2,
    const float* __restrict__ wp2, const float* __restrict__ bp2,
    float* __restrict__ x_inst, float* __restrict__ x_lag) {
  const int b = blockIdx.x;
  const int tid = threadIdx.x;
  __shared__ float Xb[TS][NN];       // 20KB
  __shared__ float xx[TS][HID];
  __shared__ float qkv[TS][192];
  __shared__ float sc[4][TS][TS];
  __shared__ float tmp[TS][HID];
  __shared__ float buf2[TS][HID];
  __shared__ float mu_s[TS], rs_s[TS];

  for (int i = tid; i < TS * NN; i += 256) Xb[i >> 9][i & 511] = X[b * TS * NN + i];
  __syncthreads();
  // x = X @ wp1 + bp1  (per row s)
  for (int o = tid; o < TS * HID; o += 256) {
    int s = o >> 6, c = o & 63;
    float acc = bp1[c];
    for (int n = 0; n < NN; n++) acc += Xb[s][n] * wp1[n * HID + c];
    xx[s][c] = acc;
  }
  __syncthreads();

  for (int l = 0; l < 2; l++) {
    const float* inw = in_w + l * HID * 192; const float* inb = in_b + l * 192;
    const float* ow  = out_w + l * HID * HID; const float* ob = out_b + l * HID;
    const float* w1  = l1_w + l * HID * HID; const float* bb1 = l1_b + l * HID;
    const float* w2  = l2_w + l * HID * HID; const float* bb2 = l2_b + l * HID;
    const float* gg1 = g1 + l * HID; const float* be1 = b1 + l * HID;
    const float* gg2 = g2 + l * HID; const float* be2 = b2 + l * HID;

    // qkv = x @ in_w + in_b
    for (int o = tid; o < TS * 192; o += 256) {
      int s = o / 192, c = o % 192;
      float acc = inb[c];
      for (int k = 0; k < HID; k++) acc += xx[s][k] * inw[k * 192 + c];
      qkv[s][c] = acc;
    }
    __syncthreads();
    // scores[h][r][t] = q[r]·k[t] / 4
    for (int o = tid; o < 400; o += 256) {
      int h = o / 100, r = (o / 10) % 10, t = o % 10;
      float acc = 0.0f;
      for (int d = 0; d < 16; d++) acc += qkv[r][h * 16 + d] * qkv[t][64 + h * 16 + d];
      sc[h][r][t] = acc * 0.25f;
    }
    __syncthreads();
    // softmax over t
    if (tid < 40) {
      int h = tid / 10, r = tid % 10;
      float m = -1e30f;
      for (int t = 0; t < 10; t++) m = fmaxf(m, sc[h][r][t]);
      float e[10], sum = 0.0f;
      for (int t = 0; t < 10; t++) { e[t] = expf(sc[h][r][t] - m); sum += e[t]; }
      float inv = 1.0f / sum;
      for (int t = 0; t < 10; t++) sc[h][r][t] = e[t] * inv;
    }
    __syncthreads();
    // o = att @ v
    for (int o = tid; o < TS * HID; o += 256) {
      int s = o >> 6, c = o & 63, h = c >> 4;
      float acc = 0.0f;
      for (int t = 0; t < 10; t++) acc += sc[h][s][t] * qkv[t][128 + c];
      tmp[s][c] = acc;
    }
    __syncthreads();
    // proj + residual
    for (int o = tid; o < TS * HID; o += 256) {
      int s = o >> 6, c = o & 63;
      float acc = ob[c] + xx[s][c];
      for (int k = 0; k < HID; k++) acc += tmp[s][k] * ow[k * HID + c];
      buf2[s][c] = acc;
    }
    __syncthreads();
    // LN1
    if (tid < 10) {
      float m = 0.0f;
      for (int c = 0; c < HID; c++) m += buf2[tid][c];
      m *= (1.0f / 64.0f);
      float v = 0.0f;
      for (int c = 0; c < HID; c++) { float d = buf2[tid][c] - m; v += d * d; }
      v *= (1.0f / 64.0f);
      mu_s[tid] = m; rs_s[tid] = rsqrtf(v + 1e-5f);
    }
    __syncthreads();
    for (int o = tid; o < TS * HID; o += 256) {
      int s = o >> 6, c = o & 63;
      xx[s][c] = (buf2[s][c] - mu_s[s]) * rs_s[s] * gg1[c] + be1[c];
    }
    __syncthreads();
    // FF
    for (int o = tid; o < TS * HID; o += 256) {
      int s = o >> 6, c = o & 63;
      float acc = bb1[c];
      for (int k = 0; k < HID; k++) acc += xx[s][k] * w1[k * HID + c];
      tmp[s][c] = fmaxf(acc, 0.0f);
    }
    __syncthreads();
    for (int o = tid; o < TS * HID; o += 256) {
      int s = o >> 6, c = o & 63;
      float acc = bb2[c] + xx[s][c];
      for (int k = 0; k < HID; k++) acc += tmp[s][k] * w2[k * HID + c];
      buf2[s][c] = acc;
    }
    __syncthreads();
    // LN2
    if (tid < 10) {
      float m = 0.0f;
      for (int c = 0; c < HID; c++) m += buf2[tid][c];
      m *= (1.0f / 64.0f);
      float v = 0.0f;
      for (int c = 0; c < HID; c++) { float d = buf2[tid][c] - m; v += d * d; }
      v *= (1.0f / 64.0f);
      mu_s[tid] = m; rs_s[tid] = rsqrtf(v + 1e-5f);
    }
    __syncthreads();
    for (int o = tid; o < TS * HID; o += 256) {
      int s = o >> 6, c = o & 63;
      xx[s][c] = (buf2[s][c] - mu_s[s]) * rs_s[s] * gg2[c] + be2[c];
    }
    __syncthreads();
  }

  // x @ wp2 + bp2; x_inst = row t=0, x_lag = mean rows 1..9
  for (int n = tid; n < NN; n += 256) {
    float accs[10];
    #pragma unroll
    for (int s = 0; s < 10; s++) accs[s] = 0.0f;
    for (int k = 0; k < HID; k++) {
      float w = wp2[k * NN + n];
      #pragma unroll
      for (int s = 0; s < 10; s++) accs[s] += xx[s][k] * w;
    }
    float bias = bp2[n];
    x_inst[b * NN + n] = accs[0] + bias;
    float lag = 0.0f;
    for (int s = 1; s < 10; s++) lag += accs[s];
    x_lag[b * NN + n] = lag * (1.0f / 9.0f) + bias;
  }
}

// ---------------- adjacency: gram + gumbel + softmax + sigmoid -----------------
__global__ __launch_bounds__(256) void adj_kernel(
    const float* __restrict__ x_inst, const float* __restrict__ x_lag,
    const float* __restrict__ es_now, const float* __restrict__ es_lag,
    const float* __restrict__ prior, float* __restrict__ out) {
  const int k = blockIdx.x & 511;
  const int v = blockIdx.x >> 9;       // 0 = now, 1 = lag
  const int tid = threadIdx.x;
  const float* xs = v ? x_lag : x_inst;
  const float* es = v ? es_lag : es_now;
  __shared__ float ck[BAT];
  __shared__ float red[4];
  if (tid < BAT) ck[tid] = xs[tid * NN + k];
  __syncthreads();
  // split(key(42)) foldlike: key_v = threefry((0,42),(0,v))
  uint32_t ka, kb, t0, t1;
  threefry2x32(0u, 42u, 0u, (uint32_t)v, ka, kb);
  float vals[2];
  #pragma unroll
  for (int jj = 0; jj < 2; jj++) {
    int j = tid + jj * 256;
    float acc = 0.0f;
    for (int bb = 0; bb < BAT; bb++) acc += ck[bb] * xs[bb * NN + j];
    if (v) acc = sigmoidf_(acc);
    threefry2x32(ka, kb, 0u, (uint32_t)(k * NN + j), t0, t1);
    // partitionable random_bits(32) = bits1 ^ bits2 (XOR-fold of the two output words)
    vals[jj] = acc + gumbel_bits(t0 ^ t1);
  }
  float m = block_red256(fmaxf(vals[0], vals[1]), red, true);
  float e0 = expf(vals[0] - m), e1 = expf(vals[1] - m);
  float s = block_red256(e0 + e1, red, false);
  float inv = 1.0f / s;
  #pragma unroll
  for (int jj = 0; jj < 2; jj++) {
    int j = tid + jj * 256;
    float a = (jj ? e1 : e0) * inv;
    float t = es[k * NN + j] + prior[k * NN + j] + a;
    float sg = sigmoidf_(t);
    sg = fminf(fmaxf(sg, 0.0f), 1.0f);
    if (j == k) sg = 0.0f;
    if (sg == 0.0f) sg = 1e-8f;
    out[v * NN * NN + k * NN + j] = sg;
  }
}

// ---------------- RealNVP flow: z2' = sigmoid(z1@fs+b)*z2 + z1@ft+b ------------
__global__ __launch_bounds__(128) void flow_kernel(
    const float* __restrict__ Z, const float* __restrict__ fs_w, const float* __restrict__ fs_b,
    const float* __restrict__ ft_w, const float* __restrict__ ft_b, float* __restrict__ z2p) {
  const int n = blockIdx.x, c = threadIdx.x;
  __shared__ float z1[128];
  z1[c] = Z[n * LAT + c];
  __syncthreads();
  float a = fs_b[c], t = ft_b[c];
  for (int k = 0; k < 128; k++) {
    float zz = z1[k];
    a += zz * fs_w[k * 128 + c];
    t += zz * ft_w[k * 128 + c];
  }
  z2p[n * 128 + c] = sigmoidf_(a) * Z[n * LAT + 128 + c] + t;
}

// ---------------- temb + GRU + time-pool, one block per node -------------------
__global__ __launch_bounds__(256) void gru_kernel(
    const int* __restrict__ tctx, const float* __restrict__ w_ih, const float* __restrict__ w_hh,
    const float* __restrict__ b_ih, const float* __restrict__ b_hh,
    const float* __restrict__ tp_w, const float* __restrict__ tp_b,
    const float* __restrict__ z2p, float* __restrict__ z2f) {
  const int n = blockIdx.x, tid = threadIdx.x;
  __shared__ float temb[TS][LAT];
  __shared__ float gi[TS][384];
  __shared__ float h[128];
  __shared__ float gh[384];
  __shared__ float freqs[128];
  __shared__ float tcf[TS];
  if (tid < 128) freqs[tid] = (float)exp((double)tid * (10.0 / 127.0));  // np-style f64 -> f32
  if (tid < TS) tcf[tid] = (float)tctx[n * TS + tid];
  if (tid < 128) h[tid] = 0.0f;
  __syncthreads();
  for (int o = tid; o < TS * LAT; o += 256) {
    int t = o >> 8, c = o & 255, cc = c & 127;
    float arg = tcf[t] * freqs[cc];
    temb[t][c] = (c < 128) ? sinf(arg) : cosf(arg);
  }
  __syncthreads();
  // gi = temb @ w_ih + b_ih, column-major thread assignment so w_ih is read once
  for (int c = tid; c < 384; c += 256) {
    float acc[10];
    float bi = b_ih[c];
    #pragma unroll
    for (int t = 0; t < 10; t++) acc[t] = bi;
    for (int k = 0; k < LAT; k++) {
      float w = w_ih[k * 384 + c];
      #pragma unroll
      for (int t = 0; t < 10; t++) acc[t] += temb[t][k] * w;
    }
    #pragma unroll
    for (int t = 0; t < 10; t++) gi[t][c] = acc[t];
  }
  float acc_tp = 0.0f;
  __syncthreads();
  for (int t = 0; t < TS; t++) {
    for (int c = tid; c < 384; c += 256) {
      float acc = b_hh[c];
      for (int k = 0; k < 128; k++) acc += h[k] * w_hh[k * 384 + c];
      gh[c] = acc;
    }
    __syncthreads();
    if (tid < 128) {
      int c = tid;
      float r = sigmoidf_(gi[t][c] + gh[c]);
      float z = sigmoidf_(gi[t][128 + c] + gh[128 + c]);
      float nn2 = tanhf(gi[t][256 + c] + r * gh[256 + c]);
      float hn = (1.0f - z) * nn2 + z * h[c];
      h[c] = hn;
      acc_tp += hn * tp_w[t];
    }
    __syncthreads();
  }
  if (tid < 128) z2f[n * 128 + tid] = z2p[n * 128 + tid] + acc_tp + tp_b[0];
}

// ---------------- Zn = concat(z1,z2f)@ltn + b; xl/xr = Zn@gat_w{l,r}+b ---------
__global__ __launch_bounds__(256) void zn_kernel(
    const float* __restrict__ Z, const float* __restrict__ z2f,
    const float* __restrict__ ltn_w, const float* __restrict__ ltn_b,
    const float* __restrict__ wl, const float* __restrict__ bl,
    const float* __restrict__ wr, const float* __restrict__ br,
    float* __restrict__ xl, float* __restrict__ xr) {
  const int n = blockIdx.x, tid = threadIdx.x;
  __shared__ float zrow[LAT];
  __shared__ float znrow[NN];
  if (tid < 128) { zrow[tid] = Z[n * LAT + tid]; zrow[128 + tid] = z2f[n * 128 + tid]; }
  __syncthreads();
  for (int o = tid; o < NN; o += 256) {
    float acc = ltn_b[o];
    for (int k = 0; k < LAT; k++) acc += zrow[k] * ltn_w[k * NN + o];
    znrow[o] = acc;
  }
  __syncthreads();
  {
    int o = tid;  // 256 cols
    float a = bl[o], bacc = br[o];
    for (int k = 0; k < NN; k++) {
      float z = znrow[k];
      a += z * wl[k * 256 + o];
      bacc += z * wr[k * 256 + o];
    }
    xl[n * 256 + o] = a;
    xr[n * 256 + o] = bacc;
  }
}

// ---------------- GATv2 + output head, one block per target node i -------------
__global__ __launch_bounds__(256) void gat_kernel(
    const float* __restrict__ xl, const float* __restrict__ xr,
    const float* __restrict__ attw, const float* __restrict__ gbias,
    const float* __restrict__ gl_w, const float* __restrict__ gl_b,
    float* __restrict__ out_mean, float* __restrict__ out_scale) {
  const int i = blockIdx.x, tid = threadIdx.x;
  __shared__ float xri[256];
  __shared__ float aw[256];
  __shared__ float e[NN][4];
  __shared__ float xe[256];
  __shared__ float red[4];
  xri[tid] = xr[i * 256 + tid];
  aw[tid] = attw[tid];
  __syncthreads();
  for (int j = tid; j < NN; j += 256) {
    const float* xlr = xl + j * 256;
    #pragma unroll
    for (int hh = 0; hh < 4; hh++) {
      float acc = 0.0f;
      for (int c = 0; c < 64; c++) {
        float v = xri[hh * 64 + c] + xlr[hh * 64 + c];
        v = (v >= 0.0f) ? v : 0.2f * v;
        acc += v * aw[hh * 64 + c];
      }
      e[j][hh] = acc;
    }
  }
  __syncthreads();
  // softmax over j per head
  for (int hh = 0; hh < 4; hh++) {
    float v0 = e[tid][hh], v1 = e[tid + 256][hh];
    float m = block_red256(fmaxf(v0, v1), red, true);
    float e0 = expf(v0 - m), e1 = expf(v1 - m);
    float s = block_red256(e0 + e1, red, false);
    float inv = 1.0f / s;
    e[tid][hh] = e0 * inv;
    e[tid + 256][hh] = e1 * inv;
  }
  __syncthreads();
  // x_emb = alpha @ xl + gat_bias
  {
    int o = tid, hh = o >> 6;
    float acc = 0.0f;
    for (int j = 0; j < NN; j++) acc += e[j][hh] * xl[j * 256 + o];
    xe[o] = acc + gbias[o];
  }
  __syncthreads();
  // ml = x_emb @ gl_w + gl_b; mean / scale
  {
    float a0 = gl_b[tid], a1 = gl_b[tid + 256], a2 = gl_b[tid + 512], a3 = gl_b[tid + 768];
    for (int k = 0; k < 256; k++) {
      float x = xe[k];
      const float* g = gl_w + k * 1024 + tid;
      a0 += x * g[0];
      a1 += x * g[256];
      a2 += x * g[512];
      a3 += x * g[768];
    }
    out_mean[i * NN + tid] = a0;
    out_mean[i * NN + tid + 256] = a1;
    float lv2 = fminf(fmaxf(a2, -5.0f), 2.0f);
    float lv3 = fminf(fmaxf(a3, -5.0f), 2.0f);
    out_scale[i * NN + tid] = expf(0.5f * lv2);
    out_scale[i * NN + tid + 256] = expf(0.5f * lv3);
  }
}

extern "C" void kernel_launch(void* const* d_in, const int* in_sizes, int n_in,
                              void* d_out, int out_size, void* d_ws, size_t ws_size,
                              hipStream_t stream) {
  (void)in_sizes; (void)n_in; (void)out_size; (void)ws_size;
  const float* X        = (const float*)d_in[0];
  const float* Z        = (const float*)d_in[1];
  const float* es_now   = (const float*)d_in[2];
  const float* es_lag   = (const float*)d_in[3];
  const float* prior    = (const float*)d_in[4];
  const float* wp1      = (const float*)d_in[5];
  const float* bp1      = (const float*)d_in[6];
  const float* enc_in_w = (const float*)d_in[7];
  const float* enc_in_b = (const float*)d_in[8];
  const float* enc_out_w= (const float*)d_in[9];
  const float* enc_out_b= (const float*)d_in[10];
  const float* enc_l1_w = (const float*)d_in[11];
  const float* enc_l1_b = (const float*)d_in[12];
  const float* enc_l2_w = (const float*)d_in[13];
  const float* enc_l2_b = (const float*)d_in[14];
  const float* enc_g1   = (const float*)d_in[15];
  const float* enc_b1   = (const float*)d_in[16];
  const float* enc_g2   = (const float*)d_in[17];
  const float* enc_b2   = (const float*)d_in[18];
  const float* wp2      = (const float*)d_in[19];
  const float* bp2      = (const float*)d_in[20];
  const float* fs_w     = (const float*)d_in[21];
  const float* fs_b     = (const float*)d_in[22];
  const float* ft_w     = (const float*)d_in[23];
  const float* ft_b     = (const float*)d_in[24];
  const float* gru_w_ih = (const float*)d_in[25];
  const float* gru_w_hh = (const float*)d_in[26];
  const float* gru_b_ih = (const float*)d_in[27];
  const float* gru_b_hh = (const float*)d_in[28];
  const float* tp_w     = (const float*)d_in[29];
  const float* tp_b     = (const float*)d_in[30];
  const float* ltn_w    = (const float*)d_in[31];
  const float* ltn_b    = (const float*)d_in[32];
  const float* gat_wl   = (const float*)d_in[33];
  const float* gat_bl   = (const float*)d_in[34];
  const float* gat_wr   = (const float*)d_in[35];
  const float* gat_br   = (const float*)d_in[36];
  const float* gat_att  = (const float*)d_in[37];
  const float* gat_bias = (const float*)d_in[38];
  const float* gl_w     = (const float*)d_in[39];
  const float* gl_b     = (const float*)d_in[40];
  const int*   tctx     = (const int*)d_in[41];

  float* out = (float*)d_out;
  float* ws  = (float*)d_ws;
  // ws layout (floats)
  float* x_inst = ws;                // 64*512
  float* x_lag  = ws + 32768;        // 64*512
  float* z2p    = ws + 65536;        // 512*128
  float* z2f    = ws + 131072;       // 512*128
  float* xl     = ws + 196608;       // 512*256
  float* xr     = ws + 327680;       // 512*256

  enc_kernel<<<dim3(BAT), dim3(256), 0, stream>>>(
      X, wp1, bp1, enc_in_w, enc_in_b, enc_out_w, enc_out_b,
      enc_l1_w, enc_l1_b, enc_l2_w, enc_l2_b,
      enc_g1, enc_b1, enc_g2, enc_b2, wp2, bp2, x_inst, x_lag);
  adj_kernel<<<dim3(2 * NN), dim3(256), 0, stream>>>(
      x_inst, x_lag, es_now, es_lag, prior, out);
  flow_kernel<<<dim3(NN), dim3(128), 0, stream>>>(Z, fs_w, fs_b, ft_w, ft_b, z2p);
  gru_kernel<<<dim3(NN), dim3(256), 0, stream>>>(
      tctx, gru_w_ih, gru_w_hh, gru_b_ih, gru_b_hh, tp_w, tp_b, z2p, z2f);
  zn_kernel<<<dim3(NN), dim3(256), 0, stream>>>(
      Z, z2f, ltn_w, ltn_b, gat_wl, gat_bl, gat_wr, gat_br, xl, xr);
  gat_kernel<<<dim3(NN), dim3(256), 0, stream>>>(
      xl, xr, gat_att, gat_bias, gl_w, gl_b, out + 2 * NN * NN, out + 3 * NN * NN);
}

// Round 3
// 267.595 us; speedup vs baseline: 1.2327x; 1.2327x over previous
//
#include <hip/hip_runtime.h>
#include <stdint.h>
#include <math.h>

// Sizes
#define NN 512   // N_NODES
#define HID 64
#define LAT 256
#define TS 10
#define BAT 64

#define DEVFN static __device__ __forceinline__

DEVFN uint32_t rotl32(uint32_t v, int d) { return (v << d) | (v >> (32 - d)); }

// Threefry-2x32, 20 rounds (JAX threefry2x32_p). key=(k0,k1), count=(x0,x1).
DEVFN void threefry2x32(uint32_t k0, uint32_t k1, uint32_t x0, uint32_t x1,
                        uint32_t& o0, uint32_t& o1) {
  uint32_t ks0 = k0, ks1 = k1, ks2 = k0 ^ k1 ^ 0x1BD11BDAu;
  x0 += ks0; x1 += ks1;
  x0 += x1; x1 = rotl32(x1, 13); x1 ^= x0;
  x0 += x1; x1 = rotl32(x1, 15); x1 ^= x0;
  x0 += x1; x1 = rotl32(x1, 26); x1 ^= x0;
  x0 += x1; x1 = rotl32(x1, 6);  x1 ^= x0;
  x0 += ks1; x1 += ks2 + 1u;
  x0 += x1; x1 = rotl32(x1, 17); x1 ^= x0;
  x0 += x1; x1 = rotl32(x1, 29); x1 ^= x0;
  x0 += x1; x1 = rotl32(x1, 16); x1 ^= x0;
  x0 += x1; x1 = rotl32(x1, 24); x1 ^= x0;
  x0 += ks2; x1 += ks0 + 2u;
  x0 += x1; x1 = rotl32(x1, 13); x1 ^= x0;
  x0 += x1; x1 = rotl32(x1, 15); x1 ^= x0;
  x0 += x1; x1 = rotl32(x1, 26); x1 ^= x0;
  x0 += x1; x1 = rotl32(x1, 6);  x1 ^= x0;
  x0 += ks0; x1 += ks1 + 3u;
  x0 += x1; x1 = rotl32(x1, 17); x1 ^= x0;
  x0 += x1; x1 = rotl32(x1, 29); x1 ^= x0;
  x0 += x1; x1 = rotl32(x1, 16); x1 ^= x0;
  x0 += x1; x1 = rotl32(x1, 24); x1 ^= x0;
  x0 += ks1; x1 += ks2 + 4u;
  x0 += x1; x1 = rotl32(x1, 13); x1 ^= x0;
  x0 += x1; x1 = rotl32(x1, 15); x1 ^= x0;
  x0 += x1; x1 = rotl32(x1, 26); x1 ^= x0;
  x0 += x1; x1 = rotl32(x1, 6);  x1 ^= x0;
  x0 += ks2; x1 += ks0 + 5u;
  o0 = x0; o1 = x1;
}

DEVFN float sigmoidf_(float x) { return 1.0f / (1.0f + expf(-x)); }

// JAX gumbel from 32 random bits: uniform in [tiny, 1), g = -log(-log(u))
DEVFN float gumbel_bits(uint32_t bits) {
  const float tiny = 1.17549435e-38f;
  float f = __uint_as_float((bits >> 9) | 0x3F800000u) - 1.0f;
  float u = f * (1.0f - tiny) + tiny;
  u = fmaxf(tiny, u);
  return -logf(-logf(u));
}

// 256-thread block reduction (4 waves of 64)
DEVFN float block_red256(float v, float* red, bool ismax) {
  #pragma unroll
  for (int o = 32; o > 0; o >>= 1) {
    float w = __shfl_down(v, o, 64);
    v = ismax ? fmaxf(v, w) : v + w;
  }
  if ((threadIdx.x & 63) == 0) red[threadIdx.x >> 6] = v;
  __syncthreads();
  float r = ismax ? fmaxf(fmaxf(red[0], red[1]), fmaxf(red[2], red[3]))
                  : ((red[0] + red[1]) + (red[2] + red[3]));
  __syncthreads();
  return r;
}

// ---------------- Transformer encoder (whole thing, one block per batch b) -----
__global__ __launch_bounds__(256) void enc_kernel(
    const float* __restrict__ X, const float* __restrict__ wp1, const float* __restrict__ bp1,
    const float* __restrict__ in_w, const float* __restrict__ in_b,
    const float* __restrict__ out_w, const float* __restrict__ out_b,
    const float* __restrict__ l1_w, const float* __restrict__ l1_b,
    const float* __restrict__ l2_w, const float* __restrict__ l2_b,
    const float* __restrict__ g1, const float* __restrict__ b1,
    const float* __restrict__ g2, const float* __restrict__ b2,
    const float* __restrict__ wp2, const float* __restrict__ bp2,
    float* __restrict__ x_inst, float* __restrict__ x_lag) {
  const int b = blockIdx.x;
  const int tid = threadIdx.x;
  __shared__ float Xb[TS][NN];       // 20KB
  __shared__ float xx[TS][HID];
  __shared__ float qkv[TS][192];
  __shared__ float sc[4][TS][TS];
  __shared__ float tmp[TS][HID];
  __shared__ float buf2[TS][HID];
  __shared__ float mu_s[TS], rs_s[TS];

  for (int i = tid; i < TS * NN; i += 256) Xb[i >> 9][i & 511] = X[b * TS * NN + i];
  __syncthreads();
  // x = X @ wp1 + bp1  (per row s)
  for (int o = tid; o < TS * HID; o += 256) {
    int s = o >> 6, c = o & 63;
    float acc = bp1[c];
    for (int n = 0; n < NN; n++) acc += Xb[s][n] * wp1[n * HID + c];
    xx[s][c] = acc;
  }
  __syncthreads();

  for (int l = 0; l < 2; l++) {
    const float* inw = in_w + l * HID * 192; const float* inb = in_b + l * 192;
    const float* ow  = out_w + l * HID * HID; const float* ob = out_b + l * HID;
    const float* w1  = l1_w + l * HID * HID; const float* bb1 = l1_b + l * HID;
    const float* w2  = l2_w + l * HID * HID; const float* bb2 = l2_b + l * HID;
    const float* gg1 = g1 + l * HID; const float* be1 = b1 + l * HID;
    const float* gg2 = g2 + l * HID; const float* be2 = b2 + l * HID;

    // qkv = x @ in_w + in_b
    for (int o = tid; o < TS * 192; o += 256) {
      int s = o / 192, c = o % 192;
      float acc = inb[c];
      for (int k = 0; k < HID; k++) acc += xx[s][k] * inw[k * 192 + c];
      qkv[s][c] = acc;
    }
    __syncthreads();
    // scores[h][r][t] = q[r]·k[t] / 4
    for (int o = tid; o < 400; o += 256) {
      int h = o / 100, r = (o / 10) % 10, t = o % 10;
      float acc = 0.0f;
      for (int d = 0; d < 16; d++) acc += qkv[r][h * 16 + d] * qkv[t][64 + h * 16 + d];
      sc[h][r][t] = acc * 0.25f;
    }
    __syncthreads();
    // softmax over t
    if (tid < 40) {
      int h = tid / 10, r = tid % 10;
      float m = -1e30f;
      for (int t = 0; t < 10; t++) m = fmaxf(m, sc[h][r][t]);
      float e[10], sum = 0.0f;
      for (int t = 0; t < 10; t++) { e[t] = expf(sc[h][r][t] - m); sum += e[t]; }
      float inv = 1.0f / sum;
      for (int t = 0; t < 10; t++) sc[h][r][t] = e[t] * inv;
    }
    __syncthreads();
    // o = att @ v
    for (int o = tid; o < TS * HID; o += 256) {
      int s = o >> 6, c = o & 63, h = c >> 4;
      float acc = 0.0f;
      for (int t = 0; t < 10; t++) acc += sc[h][s][t] * qkv[t][128 + c];
      tmp[s][c] = acc;
    }
    __syncthreads();
    // proj + residual
    for (int o = tid; o < TS * HID; o += 256) {
      int s = o >> 6, c = o & 63;
      float acc = ob[c] + xx[s][c];
      for (int k = 0; k < HID; k++) acc += tmp[s][k] * ow[k * HID + c];
      buf2[s][c] = acc;
    }
    __syncthreads();
    // LN1
    if (tid < 10) {
      float m = 0.0f;
      for (int c = 0; c < HID; c++) m += buf2[tid][c];
      m *= (1.0f / 64.0f);
      float v = 0.0f;
      for (int c = 0; c < HID; c++) { float d = buf2[tid][c] - m; v += d * d; }
      v *= (1.0f / 64.0f);
      mu_s[tid] = m; rs_s[tid] = rsqrtf(v + 1e-5f);
    }
    __syncthreads();
    for (int o = tid; o < TS * HID; o += 256) {
      int s = o >> 6, c = o & 63;
      xx[s][c] = (buf2[s][c] - mu_s[s]) * rs_s[s] * gg1[c] + be1[c];
    }
    __syncthreads();
    // FF
    for (int o = tid; o < TS * HID; o += 256) {
      int s = o >> 6, c = o & 63;
      float acc = bb1[c];
      for (int k = 0; k < HID; k++) acc += xx[s][k] * w1[k * HID + c];
      tmp[s][c] = fmaxf(acc, 0.0f);
    }
    __syncthreads();
    for (int o = tid; o < TS * HID; o += 256) {
      int s = o >> 6, c = o & 63;
      float acc = bb2[c] + xx[s][c];
      for (int k = 0; k < HID; k++) acc += tmp[s][k] * w2[k * HID + c];
      buf2[s][c] = acc;
    }
    __syncthreads();
    // LN2
    if (tid < 10) {
      float m = 0.0f;
      for (int c = 0; c < HID; c++) m += buf2[tid][c];
      m *= (1.0f / 64.0f);
      float v = 0.0f;
      for (int c = 0; c < HID; c++) { float d = buf2[tid][c] - m; v += d * d; }
      v *= (1.0f / 64.0f);
      mu_s[tid] = m; rs_s[tid] = rsqrtf(v + 1e-5f);
    }
    __syncthreads();
    for (int o = tid; o < TS * HID; o += 256) {
      int s = o >> 6, c = o & 63;
      xx[s][c] = (buf2[s][c] - mu_s[s]) * rs_s[s] * gg2[c] + be2[c];
    }
    __syncthreads();
  }

  // x @ wp2 + bp2; x_inst = row t=0, x_lag = mean rows 1..9
  for (int n = tid; n < NN; n += 256) {
    float accs[10];
    #pragma unroll
    for (int s = 0; s < 10; s++) accs[s] = 0.0f;
    for (int k = 0; k < HID; k++) {
      float w = wp2[k * NN + n];
      #pragma unroll
      for (int s = 0; s < 10; s++) accs[s] += xx[s][k] * w;
    }
    float bias = bp2[n];
    x_inst[b * NN + n] = accs[0] + bias;
    float lag = 0.0f;
    for (int s = 1; s < 10; s++) lag += accs[s];
    x_lag[b * NN + n] = lag * (1.0f / 9.0f) + bias;
  }
}

// ---------------- adjacency: gram + gumbel + softmax + sigmoid -----------------
__global__ __launch_bounds__(256) void adj_kernel(
    const float* __restrict__ x_inst, const float* __restrict__ x_lag,
    const float* __restrict__ es_now, const float* __restrict__ es_lag,
    const float* __restrict__ prior, float* __restrict__ out) {
  const int k = blockIdx.x & 511;
  const int v = blockIdx.x >> 9;       // 0 = now, 1 = lag
  const int tid = threadIdx.x;
  const float* xs = v ? x_lag : x_inst;
  const float* es = v ? es_lag : es_now;
  __shared__ float ck[BAT];
  __shared__ float red[4];
  if (tid < BAT) ck[tid] = xs[tid * NN + k];
  __syncthreads();
  // split(key(42)) foldlike: key_v = threefry((0,42),(0,v))
  uint32_t ka, kb, t0, t1;
  threefry2x32(0u, 42u, 0u, (uint32_t)v, ka, kb);
  float vals[2];
  #pragma unroll
  for (int jj = 0; jj < 2; jj++) {
    int j = tid + jj * 256;
    float acc = 0.0f;
    for (int bb = 0; bb < BAT; bb++) acc += ck[bb] * xs[bb * NN + j];
    if (v) acc = sigmoidf_(acc);
    threefry2x32(ka, kb, 0u, (uint32_t)(k * NN + j), t0, t1);
    // partitionable random_bits(32) = bits1 ^ bits2 (XOR-fold of the two output words)
    vals[jj] = acc + gumbel_bits(t0 ^ t1);
  }
  float m = block_red256(fmaxf(vals[0], vals[1]), red, true);
  float e0 = expf(vals[0] - m), e1 = expf(vals[1] - m);
  float s = block_red256(e0 + e1, red, false);
  float inv = 1.0f / s;
  #pragma unroll
  for (int jj = 0; jj < 2; jj++) {
    int j = tid + jj * 256;
    float a = (jj ? e1 : e0) * inv;
    float t = es[k * NN + j] + prior[k * NN + j] + a;
    float sg = sigmoidf_(t);
    sg = fminf(fmaxf(sg, 0.0f), 1.0f);
    if (j == k) sg = 0.0f;
    if (sg == 0.0f) sg = 1e-8f;
    out[v * NN * NN + k * NN + j] = sg;
  }
}

// ---------------- RealNVP flow: z2' = sigmoid(z1@fs+b)*z2 + z1@ft+b ------------
__global__ __launch_bounds__(128) void flow_kernel(
    const float* __restrict__ Z, const float* __restrict__ fs_w, const float* __restrict__ fs_b,
    const float* __restrict__ ft_w, const float* __restrict__ ft_b, float* __restrict__ z2p) {
  const int n = blockIdx.x, c = threadIdx.x;
  __shared__ float z1[128];
  z1[c] = Z[n * LAT + c];
  __syncthreads();
  float a = fs_b[c], t = ft_b[c];
  for (int k = 0; k < 128; k++) {
    float zz = z1[k];
    a += zz * fs_w[k * 128 + c];
    t += zz * ft_w[k * 128 + c];
  }
  z2p[n * 128 + c] = sigmoidf_(a) * Z[n * LAT + 128 + c] + t;
}

// ---------------- gi table: only 100 distinct time values exist ----------------
// gi_table[v][c] = b_ih[c] + sum_k temb(v)[k] * w_ih[k*384+c], bitwise-identical
// k-order to the per-node GEMM it replaces.
__global__ __launch_bounds__(384) void gitab_kernel(
    const float* __restrict__ w_ih, const float* __restrict__ b_ih,
    float* __restrict__ gi_table) {
  const int v = blockIdx.x;      // 0..99
  const int t = threadIdx.x;     // col 0..383
  __shared__ float temb[256];
  if (t < 256) {
    float fr = (float)exp((double)(t & 127) * (10.0 / 127.0));  // np-style f64 -> f32
    float arg = (float)v * fr;
    temb[t] = (t < 128) ? sinf(arg) : cosf(arg);
  }
  __syncthreads();
  float acc = b_ih[t];
  for (int k = 0; k < 256; k++) acc += temb[k] * w_ih[k * 384 + t];
  gi_table[v * 384 + t] = acc;
}

// ---------------- GRU: w_hh register-resident, gi via table lookup -------------
// 384 threads; thread t owns w_hh column t (128 regs). Per step: 32 broadcast
// ds_read_b128 of h + 128 FMA; n-gate keeps gi/gh separate (n = tanh(gi_n + r*gh_n)).
__global__ __launch_bounds__(384) void gru_kernel2(
    const int* __restrict__ tctx, const float* __restrict__ w_hh,
    const float* __restrict__ b_hh, const float* __restrict__ gi_table,
    const float* __restrict__ tp_w, const float* __restrict__ tp_b,
    const float* __restrict__ z2p, float* __restrict__ z2f) {
  const int n = blockIdx.x, t = threadIdx.x;
  __shared__ float h[128];
  __shared__ float sums[256];   // gi+gh for r,z cols
  __shared__ float ghn[128];    // gh for n cols
  __shared__ float gin[128];    // gi for n cols
  float whh[128];
  #pragma unroll
  for (int k = 0; k < 128; k++) whh[k] = w_hh[k * 384 + t];
  float gis[10];
  #pragma unroll
  for (int s = 0; s < 10; s++) gis[s] = gi_table[tctx[n * 10 + s] * 384 + t];
  float tpw[10];
  #pragma unroll
  for (int s = 0; s < 10; s++) tpw[s] = tp_w[s];
  const float bhh = b_hh[t];
  if (t < 128) h[t] = 0.0f;
  float acc_tp = 0.0f;
  __syncthreads();
  #pragma unroll
  for (int s = 0; s < 10; s++) {
    float acc = bhh;
    const float4* h4 = (const float4*)h;
    #pragma unroll
    for (int k4 = 0; k4 < 32; k4++) {
      float4 hv = h4[k4];
      acc += hv.x * whh[4 * k4 + 0];
      acc += hv.y * whh[4 * k4 + 1];
      acc += hv.z * whh[4 * k4 + 2];
      acc += hv.w * whh[4 * k4 + 3];
    }
    if (t < 256) sums[t] = gis[s] + acc;
    else { ghn[t - 256] = acc; gin[t - 256] = gis[s]; }
    __syncthreads();
    if (t < 128) {
      float r = sigmoidf_(sums[t]);
      float z = sigmoidf_(sums[128 + t]);
      float nn2 = tanhf(gin[t] + r * ghn[t]);
      float hn = (1.0f - z) * nn2 + z * h[t];
      h[t] = hn;
      acc_tp += hn * tpw[s];
    }
    __syncthreads();
  }
  if (t < 128) z2f[n * 128 + t] = z2p[n * 128 + t] + acc_tp + tp_b[0];
}

// ---------------- Zn = concat(z1,z2f)@ltn + b; xl/xr = Zn@gat_w{l,r}+b ---------
__global__ __launch_bounds__(256) void zn_kernel(
    const float* __restrict__ Z, const float* __restrict__ z2f,
    const float* __restrict__ ltn_w, const float* __restrict__ ltn_b,
    const float* __restrict__ wl, const float* __restrict__ bl,
    const float* __restrict__ wr, const float* __restrict__ br,
    float* __restrict__ xl, float* __restrict__ xr) {
  const int n = blockIdx.x, tid = threadIdx.x;
  __shared__ float zrow[LAT];
  __shared__ float znrow[NN];
  if (tid < 128) { zrow[tid] = Z[n * LAT + tid]; zrow[128 + tid] = z2f[n * 128 + tid]; }
  __syncthreads();
  for (int o = tid; o < NN; o += 256) {
    float acc = ltn_b[o];
    for (int k = 0; k < LAT; k++) acc += zrow[k] * ltn_w[k * NN + o];
    znrow[o] = acc;
  }
  __syncthreads();
  {
    int o = tid;  // 256 cols
    float a = bl[o], bacc = br[o];
    for (int k = 0; k < NN; k++) {
      float z = znrow[k];
      a += z * wl[k * 256 + o];
      bacc += z * wr[k * 256 + o];
    }
    xl[n * 256 + o] = a;
    xr[n * 256 + o] = bacc;
  }
}

// ---------------- GATv2 + output head, one block per target node i -------------
__global__ __launch_bounds__(256) void gat_kernel(
    const float* __restrict__ xl, const float* __restrict__ xr,
    const float* __restrict__ attw, const float* __restrict__ gbias,
    const float* __restrict__ gl_w, const float* __restrict__ gl_b,
    float* __restrict__ out_mean, float* __restrict__ out_scale) {
  const int i = blockIdx.x, tid = threadIdx.x;
  __shared__ float xri[256];
  __shared__ float aw[256];
  __shared__ float e[NN][4];
  __shared__ float xe[256];
  __shared__ float red[4];
  xri[tid] = xr[i * 256 + tid];
  aw[tid] = attw[tid];
  __syncthreads();
  for (int j = tid; j < NN; j += 256) {
    const float* xlr = xl + j * 256;
    #pragma unroll
    for (int hh = 0; hh < 4; hh++) {
      float acc = 0.0f;
      for (int c = 0; c < 64; c++) {
        float v = xri[hh * 64 + c] + xlr[hh * 64 + c];
        v = (v >= 0.0f) ? v : 0.2f * v;
        acc += v * aw[hh * 64 + c];
      }
      e[j][hh] = acc;
    }
  }
  __syncthreads();
  // softmax over j per head
  for (int hh = 0; hh < 4; hh++) {
    float v0 = e[tid][hh], v1 = e[tid + 256][hh];
    float m = block_red256(fmaxf(v0, v1), red, true);
    float e0 = expf(v0 - m), e1 = expf(v1 - m);
    float s = block_red256(e0 + e1, red, false);
    float inv = 1.0f / s;
    e[tid][hh] = e0 * inv;
    e[tid + 256][hh] = e1 * inv;
  }
  __syncthreads();
  // x_emb = alpha @ xl + gat_bias
  {
    int o = tid, hh = o >> 6;
    float acc = 0.0f;
    for (int j = 0; j < NN; j++) acc += e[j][hh] * xl[j * 256 + o];
    xe[o] = acc + gbias[o];
  }
  __syncthreads();
  // ml = x_emb @ gl_w + gl_b; mean / scale
  {
    float a0 = gl_b[tid], a1 = gl_b[tid + 256], a2 = gl_b[tid + 512], a3 = gl_b[tid + 768];
    for (int k = 0; k < 256; k++) {
      float x = xe[k];
      const float* g = gl_w + k * 1024 + tid;
      a0 += x * g[0];
      a1 += x * g[256];
      a2 += x * g[512];
      a3 += x * g[768];
    }
    out_mean[i * NN + tid] = a0;
    out_mean[i * NN + tid + 256] = a1;
    float lv2 = fminf(fmaxf(a2, -5.0f), 2.0f);
    float lv3 = fminf(fmaxf(a3, -5.0f), 2.0f);
    out_scale[i * NN + tid] = expf(0.5f * lv2);
    out_scale[i * NN + tid + 256] = expf(0.5f * lv3);
  }
}

extern "C" void kernel_launch(void* const* d_in, const int* in_sizes, int n_in,
                              void* d_out, int out_size, void* d_ws, size_t ws_size,
                              hipStream_t stream) {
  (void)in_sizes; (void)n_in; (void)out_size; (void)ws_size;
  const float* X        = (const float*)d_in[0];
  const float* Z        = (const float*)d_in[1];
  const float* es_now   = (const float*)d_in[2];
  const float* es_lag   = (const float*)d_in[3];
  const float* prior    = (const float*)d_in[4];
  const float* wp1      = (const float*)d_in[5];
  const float* bp1      = (const float*)d_in[6];
  const float* enc_in_w = (const float*)d_in[7];
  const float* enc_in_b = (const float*)d_in[8];
  const float* enc_out_w= (const float*)d_in[9];
  const float* enc_out_b= (const float*)d_in[10];
  const float* enc_l1_w = (const float*)d_in[11];
  const float* enc_l1_b = (const float*)d_in[12];
  const float* enc_l2_w = (const float*)d_in[13];
  const float* enc_l2_b = (const float*)d_in[14];
  const float* enc_g1   = (const float*)d_in[15];
  const float* enc_b1   = (const float*)d_in[16];
  const float* enc_g2   = (const float*)d_in[17];
  const float* enc_b2   = (const float*)d_in[18];
  const float* wp2      = (const float*)d_in[19];
  const float* bp2      = (const float*)d_in[20];
  const float* fs_w     = (const float*)d_in[21];
  const float* fs_b     = (const float*)d_in[22];
  const float* ft_w     = (const float*)d_in[23];
  const float* ft_b     = (const float*)d_in[24];
  const float* gru_w_ih = (const float*)d_in[25];
  const float* gru_w_hh = (const float*)d_in[26];
  const float* gru_b_ih = (const float*)d_in[27];
  const float* gru_b_hh = (const float*)d_in[28];
  const float* tp_w     = (const float*)d_in[29];
  const float* tp_b     = (const float*)d_in[30];
  const float* ltn_w    = (const float*)d_in[31];
  const float* ltn_b    = (const float*)d_in[32];
  const float* gat_wl   = (const float*)d_in[33];
  const float* gat_bl   = (const float*)d_in[34];
  const float* gat_wr   = (const float*)d_in[35];
  const float* gat_br   = (const float*)d_in[36];
  const float* gat_att  = (const float*)d_in[37];
  const float* gat_bias = (const float*)d_in[38];
  const float* gl_w     = (const float*)d_in[39];
  const float* gl_b     = (const float*)d_in[40];
  const int*   tctx     = (const int*)d_in[41];

  float* out = (float*)d_out;
  float* ws  = (float*)d_ws;
  // ws layout (floats)
  float* x_inst   = ws;                // 64*512
  float* x_lag    = ws + 32768;        // 64*512
  float* z2p      = ws + 65536;        // 512*128
  float* z2f      = ws + 131072;       // 512*128
  float* xl       = ws + 196608;       // 512*256
  float* xr       = ws + 327680;       // 512*256
  float* gi_table = ws + 458752;       // 100*384

  gitab_kernel<<<dim3(100), dim3(384), 0, stream>>>(gru_w_ih, gru_b_ih, gi_table);
  flow_kernel<<<dim3(NN), dim3(128), 0, stream>>>(Z, fs_w, fs_b, ft_w, ft_b, z2p);
  enc_kernel<<<dim3(BAT), dim3(256), 0, stream>>>(
      X, wp1, bp1, enc_in_w, enc_in_b, enc_out_w, enc_out_b,
      enc_l1_w, enc_l1_b, enc_l2_w, enc_l2_b,
      enc_g1, enc_b1, enc_g2, enc_b2, wp2, bp2, x_inst, x_lag);
  adj_kernel<<<dim3(2 * NN), dim3(256), 0, stream>>>(
      x_inst, x_lag, es_now, es_lag, prior, out);
  gru_kernel2<<<dim3(NN), dim3(384), 0, stream>>>(
      tctx, gru_w_hh, gru_b_hh, gi_table, tp_w, tp_b, z2p, z2f);
  zn_kernel<<<dim3(NN), dim3(256), 0, stream>>>(
      Z, z2f, ltn_w, ltn_b, gat_wl, gat_bl, gat_wr, gat_br, xl, xr);
  gat_kernel<<<dim3(NN), dim3(256), 0, stream>>>(
      xl, xr, gat_att, gat_bias, gl_w, gl_b, out + 2 * NN * NN, out + 3 * NN * NN);
}

// Round 4
// 254.007 us; speedup vs baseline: 1.2987x; 1.0535x over previous
//
#include <hip/hip_runtime.h>
#include <stdint.h>
#include <math.h>

// Sizes
#define NN 512   // N_NODES
#define HID 64
#define LAT 256
#define TS 10
#define BAT 64

#define DEVFN static __device__ __forceinline__

DEVFN uint32_t rotl32(uint32_t v, int d) { return (v << d) | (v >> (32 - d)); }

// Threefry-2x32, 20 rounds (JAX threefry2x32_p). key=(k0,k1), count=(x0,x1).
DEVFN void threefry2x32(uint32_t k0, uint32_t k1, uint32_t x0, uint32_t x1,
                        uint32_t& o0, uint32_t& o1) {
  uint32_t ks0 = k0, ks1 = k1, ks2 = k0 ^ k1 ^ 0x1BD11BDAu;
  x0 += ks0; x1 += ks1;
  x0 += x1; x1 = rotl32(x1, 13); x1 ^= x0;
  x0 += x1; x1 = rotl32(x1, 15); x1 ^= x0;
  x0 += x1; x1 = rotl32(x1, 26); x1 ^= x0;
  x0 += x1; x1 = rotl32(x1, 6);  x1 ^= x0;
  x0 += ks1; x1 += ks2 + 1u;
  x0 += x1; x1 = rotl32(x1, 17); x1 ^= x0;
  x0 += x1; x1 = rotl32(x1, 29); x1 ^= x0;
  x0 += x1; x1 = rotl32(x1, 16); x1 ^= x0;
  x0 += x1; x1 = rotl32(x1, 24); x1 ^= x0;
  x0 += ks2; x1 += ks0 + 2u;
  x0 += x1; x1 = rotl32(x1, 13); x1 ^= x0;
  x0 += x1; x1 = rotl32(x1, 15); x1 ^= x0;
  x0 += x1; x1 = rotl32(x1, 26); x1 ^= x0;
  x0 += x1; x1 = rotl32(x1, 6);  x1 ^= x0;
  x0 += ks0; x1 += ks1 + 3u;
  x0 += x1; x1 = rotl32(x1, 17); x1 ^= x0;
  x0 += x1; x1 = rotl32(x1, 29); x1 ^= x0;
  x0 += x1; x1 = rotl32(x1, 16); x1 ^= x0;
  x0 += x1; x1 = rotl32(x1, 24); x1 ^= x0;
  x0 += ks1; x1 += ks2 + 4u;
  x0 += x1; x1 = rotl32(x1, 13); x1 ^= x0;
  x0 += x1; x1 = rotl32(x1, 15); x1 ^= x0;
  x0 += x1; x1 = rotl32(x1, 26); x1 ^= x0;
  x0 += x1; x1 = rotl32(x1, 6);  x1 ^= x0;
  x0 += ks2; x1 += ks0 + 5u;
  o0 = x0; o1 = x1;
}

DEVFN float sigmoidf_(float x) { return 1.0f / (1.0f + expf(-x)); }

// JAX gumbel from 32 random bits: uniform in [tiny, 1), g = -log(-log(u))
DEVFN float gumbel_bits(uint32_t bits) {
  const float tiny = 1.17549435e-38f;
  float f = __uint_as_float((bits >> 9) | 0x3F800000u) - 1.0f;
  float u = f * (1.0f - tiny) + tiny;
  u = fmaxf(tiny, u);
  return -logf(-logf(u));
}

// 256-thread block reduction (4 waves of 64)
DEVFN float block_red256(float v, float* red, bool ismax) {
  #pragma unroll
  for (int o = 32; o > 0; o >>= 1) {
    float w = __shfl_down(v, o, 64);
    v = ismax ? fmaxf(v, w) : v + w;
  }
  if ((threadIdx.x & 63) == 0) red[threadIdx.x >> 6] = v;
  __syncthreads();
  float r = ismax ? fmaxf(fmaxf(red[0], red[1]), fmaxf(red[2], red[3]))
                  : ((red[0] + red[1]) + (red[2] + red[3]));
  __syncthreads();
  return r;
}

// ---------------- Transformer encoder (whole thing, one block per batch b) -----
__global__ __launch_bounds__(256) void enc_kernel(
    const float* __restrict__ X, const float* __restrict__ wp1, const float* __restrict__ bp1,
    const float* __restrict__ in_w, const float* __restrict__ in_b,
    const float* __restrict__ out_w, const float* __restrict__ out_b,
    const float* __restrict__ l1_w, const float* __restrict__ l1_b,
    const float* __restrict__ l2_w, const float* __restrict__ l2_b,
    const float* __restrict__ g1, const float* __restrict__ b1,
    const float* __restrict__ g2, const float* __restrict__ b2,
    const float* __restrict__ wp2, const float* __restrict__ bp2,
    float* __restrict__ x_inst, float* __restrict__ x_lag) {
  const int b = blockIdx.x;
  const int tid = threadIdx.x;
  __shared__ float Xb[TS][NN];       // 20KB
  __shared__ float xx[TS][HID];
  __shared__ float qkv[TS][192];
  __shared__ float sc[4][TS][TS];
  __shared__ float tmp[TS][HID];
  __shared__ float buf2[TS][HID];
  __shared__ float mu_s[TS], rs_s[TS];

  for (int i = tid; i < TS * NN; i += 256) Xb[i >> 9][i & 511] = X[b * TS * NN + i];
  __syncthreads();
  // x = X @ wp1 + bp1  (per row s)
  for (int o = tid; o < TS * HID; o += 256) {
    int s = o >> 6, c = o & 63;
    float acc = bp1[c];
    for (int n = 0; n < NN; n++) acc += Xb[s][n] * wp1[n * HID + c];
    xx[s][c] = acc;
  }
  __syncthreads();

  for (int l = 0; l < 2; l++) {
    const float* inw = in_w + l * HID * 192; const float* inb = in_b + l * 192;
    const float* ow  = out_w + l * HID * HID; const float* ob = out_b + l * HID;
    const float* w1  = l1_w + l * HID * HID; const float* bb1 = l1_b + l * HID;
    const float* w2  = l2_w + l * HID * HID; const float* bb2 = l2_b + l * HID;
    const float* gg1 = g1 + l * HID; const float* be1 = b1 + l * HID;
    const float* gg2 = g2 + l * HID; const float* be2 = b2 + l * HID;

    // qkv = x @ in_w + in_b
    for (int o = tid; o < TS * 192; o += 256) {
      int s = o / 192, c = o % 192;
      float acc = inb[c];
      for (int k = 0; k < HID; k++) acc += xx[s][k] * inw[k * 192 + c];
      qkv[s][c] = acc;
    }
    __syncthreads();
    // scores[h][r][t] = q[r]·k[t] / 4
    for (int o = tid; o < 400; o += 256) {
      int h = o / 100, r = (o / 10) % 10, t = o % 10;
      float acc = 0.0f;
      for (int d = 0; d < 16; d++) acc += qkv[r][h * 16 + d] * qkv[t][64 + h * 16 + d];
      sc[h][r][t] = acc * 0.25f;
    }
    __syncthreads();
    // softmax over t
    if (tid < 40) {
      int h = tid / 10, r = tid % 10;
      float m = -1e30f;
      for (int t = 0; t < 10; t++) m = fmaxf(m, sc[h][r][t]);
      float e[10], sum = 0.0f;
      for (int t = 0; t < 10; t++) { e[t] = expf(sc[h][r][t] - m); sum += e[t]; }
      float inv = 1.0f / sum;
      for (int t = 0; t < 10; t++) sc[h][r][t] = e[t] * inv;
    }
    __syncthreads();
    // o = att @ v
    for (int o = tid; o < TS * HID; o += 256) {
      int s = o >> 6, c = o & 63, h = c >> 4;
      float acc = 0.0f;
      for (int t = 0; t < 10; t++) acc += sc[h][s][t] * qkv[t][128 + c];
      tmp[s][c] = acc;
    }
    __syncthreads();
    // proj + residual
    for (int o = tid; o < TS * HID; o += 256) {
      int s = o >> 6, c = o & 63;
      float acc = ob[c] + xx[s][c];
      for (int k = 0; k < HID; k++) acc += tmp[s][k] * ow[k * HID + c];
      buf2[s][c] = acc;
    }
    __syncthreads();
    // LN1
    if (tid < 10) {
      float m = 0.0f;
      for (int c = 0; c < HID; c++) m += buf2[tid][c];
      m *= (1.0f / 64.0f);
      float v = 0.0f;
      for (int c = 0; c < HID; c++) { float d = buf2[tid][c] - m; v += d * d; }
      v *= (1.0f / 64.0f);
      mu_s[tid] = m; rs_s[tid] = rsqrtf(v + 1e-5f);
    }
    __syncthreads();
    for (int o = tid; o < TS * HID; o += 256) {
      int s = o >> 6, c = o & 63;
      xx[s][c] = (buf2[s][c] - mu_s[s]) * rs_s[s] * gg1[c] + be1[c];
    }
    __syncthreads();
    // FF
    for (int o = tid; o < TS * HID; o += 256) {
      int s = o >> 6, c = o & 63;
      float acc = bb1[c];
      for (int k = 0; k < HID; k++) acc += xx[s][k] * w1[k * HID + c];
      tmp[s][c] = fmaxf(acc, 0.0f);
    }
    __syncthreads();
    for (int o = tid; o < TS * HID; o += 256) {
      int s = o >> 6, c = o & 63;
      float acc = bb2[c] + xx[s][c];
      for (int k = 0; k < HID; k++) acc += tmp[s][k] * w2[k * HID + c];
      buf2[s][c] = acc;
    }
    __syncthreads();
    // LN2
    if (tid < 10) {
      float m = 0.0f;
      for (int c = 0; c < HID; c++) m += buf2[tid][c];
      m *= (1.0f / 64.0f);
      float v = 0.0f;
      for (int c = 0; c < HID; c++) { float d = buf2[tid][c] - m; v += d * d; }
      v *= (1.0f / 64.0f);
      mu_s[tid] = m; rs_s[tid] = rsqrtf(v + 1e-5f);
    }
    __syncthreads();
    for (int o = tid; o < TS * HID; o += 256) {
      int s = o >> 6, c = o & 63;
      xx[s][c] = (buf2[s][c] - mu_s[s]) * rs_s[s] * gg2[c] + be2[c];
    }
    __syncthreads();
  }

  // x @ wp2 + bp2; x_inst = row t=0, x_lag = mean rows 1..9
  for (int n = tid; n < NN; n += 256) {
    float accs[10];
    #pragma unroll
    for (int s = 0; s < 10; s++) accs[s] = 0.0f;
    for (int k = 0; k < HID; k++) {
      float w = wp2[k * NN + n];
      #pragma unroll
      for (int s = 0; s < 10; s++) accs[s] += xx[s][k] * w;
    }
    float bias = bp2[n];
    x_inst[b * NN + n] = accs[0] + bias;
    float lag = 0.0f;
    for (int s = 1; s < 10; s++) lag += accs[s];
    x_lag[b * NN + n] = lag * (1.0f / 9.0f) + bias;
  }
}

// ---------------- adjacency: gram + gumbel + softmax + sigmoid -----------------
__global__ __launch_bounds__(256) void adj_kernel(
    const float* __restrict__ x_inst, const float* __restrict__ x_lag,
    const float* __restrict__ es_now, const float* __restrict__ es_lag,
    const float* __restrict__ prior, float* __restrict__ out) {
  const int k = blockIdx.x & 511;
  const int v = blockIdx.x >> 9;       // 0 = now, 1 = lag
  const int tid = threadIdx.x;
  const float* xs = v ? x_lag : x_inst;
  const float* es = v ? es_lag : es_now;
  __shared__ float ck[BAT];
  __shared__ float red[4];
  if (tid < BAT) ck[tid] = xs[tid * NN + k];
  __syncthreads();
  // split(key(42)) foldlike: key_v = threefry((0,42),(0,v))
  uint32_t ka, kb, t0, t1;
  threefry2x32(0u, 42u, 0u, (uint32_t)v, ka, kb);
  float vals[2];
  #pragma unroll
  for (int jj = 0; jj < 2; jj++) {
    int j = tid + jj * 256;
    float acc = 0.0f;
    for (int bb = 0; bb < BAT; bb++) acc += ck[bb] * xs[bb * NN + j];
    if (v) acc = sigmoidf_(acc);
    threefry2x32(ka, kb, 0u, (uint32_t)(k * NN + j), t0, t1);
    // partitionable random_bits(32) = bits1 ^ bits2 (XOR-fold of the two output words)
    vals[jj] = acc + gumbel_bits(t0 ^ t1);
  }
  float m = block_red256(fmaxf(vals[0], vals[1]), red, true);
  float e0 = expf(vals[0] - m), e1 = expf(vals[1] - m);
  float s = block_red256(e0 + e1, red, false);
  float inv = 1.0f / s;
  #pragma unroll
  for (int jj = 0; jj < 2; jj++) {
    int j = tid + jj * 256;
    float a = (jj ? e1 : e0) * inv;
    float t = es[k * NN + j] + prior[k * NN + j] + a;
    float sg = sigmoidf_(t);
    sg = fminf(fmaxf(sg, 0.0f), 1.0f);
    if (j == k) sg = 0.0f;
    if (sg == 0.0f) sg = 1e-8f;
    out[v * NN * NN + k * NN + j] = sg;
  }
}

// ---------------- RealNVP flow: z2' = sigmoid(z1@fs+b)*z2 + z1@ft+b ------------
__global__ __launch_bounds__(128) void flow_kernel(
    const float* __restrict__ Z, const float* __restrict__ fs_w, const float* __restrict__ fs_b,
    const float* __restrict__ ft_w, const float* __restrict__ ft_b, float* __restrict__ z2p) {
  const int n = blockIdx.x, c = threadIdx.x;
  __shared__ float z1[128];
  z1[c] = Z[n * LAT + c];
  __syncthreads();
  float a = fs_b[c], t = ft_b[c];
  for (int k = 0; k < 128; k++) {
    float zz = z1[k];
    a += zz * fs_w[k * 128 + c];
    t += zz * ft_w[k * 128 + c];
  }
  z2p[n * 128 + c] = sigmoidf_(a) * Z[n * LAT + 128 + c] + t;
}

// ---------------- gi table: only 100 distinct time values exist ----------------
__global__ __launch_bounds__(384) void gitab_kernel(
    const float* __restrict__ w_ih, const float* __restrict__ b_ih,
    float* __restrict__ gi_table) {
  const int v = blockIdx.x;      // 0..99
  const int t = threadIdx.x;     // col 0..383
  __shared__ float temb[256];
  if (t < 256) {
    float fr = (float)exp((double)(t & 127) * (10.0 / 127.0));  // np-style f64 -> f32
    float arg = (float)v * fr;
    temb[t] = (t < 128) ? sinf(arg) : cosf(arg);
  }
  __syncthreads();
  float acc = b_ih[t];
  for (int k = 0; k < 256; k++) acc += temb[k] * w_ih[k * 384 + t];
  gi_table[v * 384 + t] = acc;
}

// ---------------- GRU: w_hh register-resident, gi via table lookup -------------
__global__ __launch_bounds__(384) void gru_kernel2(
    const int* __restrict__ tctx, const float* __restrict__ w_hh,
    const float* __restrict__ b_hh, const float* __restrict__ gi_table,
    const float* __restrict__ tp_w, const float* __restrict__ tp_b,
    const float* __restrict__ z2p, float* __restrict__ z2f) {
  const int n = blockIdx.x, t = threadIdx.x;
  __shared__ float h[128];
  __shared__ float sums[256];   // gi+gh for r,z cols
  __shared__ float ghn[128];    // gh for n cols
  __shared__ float gin[128];    // gi for n cols
  float whh[128];
  #pragma unroll
  for (int k = 0; k < 128; k++) whh[k] = w_hh[k * 384 + t];
  float gis[10];
  #pragma unroll
  for (int s = 0; s < 10; s++) gis[s] = gi_table[tctx[n * 10 + s] * 384 + t];
  float tpw[10];
  #pragma unroll
  for (int s = 0; s < 10; s++) tpw[s] = tp_w[s];
  const float bhh = b_hh[t];
  if (t < 128) h[t] = 0.0f;
  float acc_tp = 0.0f;
  __syncthreads();
  #pragma unroll
  for (int s = 0; s < 10; s++) {
    float acc = bhh;
    const float4* h4 = (const float4*)h;
    #pragma unroll
    for (int k4 = 0; k4 < 32; k4++) {
      float4 hv = h4[k4];
      acc += hv.x * whh[4 * k4 + 0];
      acc += hv.y * whh[4 * k4 + 1];
      acc += hv.z * whh[4 * k4 + 2];
      acc += hv.w * whh[4 * k4 + 3];
    }
    if (t < 256) sums[t] = gis[s] + acc;
    else { ghn[t - 256] = acc; gin[t - 256] = gis[s]; }
    __syncthreads();
    if (t < 128) {
      float r = sigmoidf_(sums[t]);
      float z = sigmoidf_(sums[128 + t]);
      float nn2 = tanhf(gin[t] + r * ghn[t]);
      float hn = (1.0f - z) * nn2 + z * h[t];
      h[t] = hn;
      acc_tp += hn * tpw[s];
    }
    __syncthreads();
  }
  if (t < 128) z2f[n * 128 + t] = z2p[n * 128 + t] + acc_tp + tp_b[0];
}

// ---------------- Zn = concat(z1,z2f)@ltn + b; xl/xr = Zn@gat_w{l,r}+b ---------
__global__ __launch_bounds__(256) void zn_kernel(
    const float* __restrict__ Z, const float* __restrict__ z2f,
    const float* __restrict__ ltn_w, const float* __restrict__ ltn_b,
    const float* __restrict__ wl, const float* __restrict__ bl,
    const float* __restrict__ wr, const float* __restrict__ br,
    float* __restrict__ xl, float* __restrict__ xr) {
  const int n = blockIdx.x, tid = threadIdx.x;
  __shared__ float zrow[LAT];
  __shared__ float znrow[NN];
  if (tid < 128) { zrow[tid] = Z[n * LAT + tid]; zrow[128 + tid] = z2f[n * 128 + tid]; }
  __syncthreads();
  for (int o = tid; o < NN; o += 256) {
    float acc = ltn_b[o];
    for (int k = 0; k < LAT; k++) acc += zrow[k] * ltn_w[k * NN + o];
    znrow[o] = acc;
  }
  __syncthreads();
  {
    int o = tid;  // 256 cols
    float a = bl[o], bacc = br[o];
    for (int k = 0; k < NN; k++) {
      float z = znrow[k];
      a += z * wl[k * 256 + o];
      bacc += z * wr[k * 256 + o];
    }
    xl[n * 256 + o] = a;
    xr[n * 256 + o] = bacc;
  }
}

// ---------------- GATv2 attention: e, softmax, x_emb (one block per target i) --
// e stored [4][512] (conflict-free); gl GEMM moved to glgemm_kernel.
__global__ __launch_bounds__(256) void gat_kernel2(
    const float* __restrict__ xl, const float* __restrict__ xr,
    const float* __restrict__ attw, const float* __restrict__ gbias,
    float* __restrict__ xemb) {
  const int i = blockIdx.x, tid = threadIdx.x;
  __shared__ float xri[256];
  __shared__ float aw[256];
  __shared__ float e[4][NN];   // per-head rows: conflict-free access
  __shared__ float red[4];
  xri[tid] = xr[i * 256 + tid];
  aw[tid] = attw[tid];
  __syncthreads();
  // e[h][j] = sum_c leaky(xri[h*64+c] + xl[j][h*64+c]) * aw[h*64+c]
  #pragma unroll
  for (int jj = 0; jj < 2; jj++) {
    const int j = tid + jj * 256;
    const float4* xl4 = (const float4*)(xl + j * 256);
    #pragma unroll
    for (int hh = 0; hh < 4; hh++) {
      float acc = 0.0f;
      #pragma unroll 4
      for (int c4 = 0; c4 < 16; c4++) {
        float4 v = xl4[hh * 16 + c4];
        const int cb = hh * 64 + c4 * 4;
        float a0 = xri[cb + 0] + v.x; a0 = (a0 >= 0.0f) ? a0 : 0.2f * a0;
        float a1 = xri[cb + 1] + v.y; a1 = (a1 >= 0.0f) ? a1 : 0.2f * a1;
        float a2 = xri[cb + 2] + v.z; a2 = (a2 >= 0.0f) ? a2 : 0.2f * a2;
        float a3 = xri[cb + 3] + v.w; a3 = (a3 >= 0.0f) ? a3 : 0.2f * a3;
        acc += a0 * aw[cb + 0];
        acc += a1 * aw[cb + 1];
        acc += a2 * aw[cb + 2];
        acc += a3 * aw[cb + 3];
      }
      e[hh][j] = acc;
    }
  }
  __syncthreads();
  // softmax over j per head
  for (int hh = 0; hh < 4; hh++) {
    float v0 = e[hh][tid], v1 = e[hh][tid + 256];
    float m = block_red256(fmaxf(v0, v1), red, true);
    float e0 = expf(v0 - m), e1 = expf(v1 - m);
    float s = block_red256(e0 + e1, red, false);
    float inv = 1.0f / s;
    e[hh][tid] = e0 * inv;
    e[hh][tid + 256] = e1 * inv;
  }
  __syncthreads();
  // x_emb[i][o] = sum_j alpha[h(o)][j] * xl[j][o] + gbias[o]
  {
    const int o = tid, hh = o >> 6;
    float acc = 0.0f;
    #pragma unroll 8
    for (int j = 0; j < NN; j++) acc += e[hh][j] * xl[j * 256 + o];
    xemb[i * 256 + o] = acc + gbias[o];
  }
}

// ---------------- ml = x_emb @ gl_w + gl_b (tiled); mean/scale epilogue --------
// grid: 32 i-tiles (16 rows) x 16 col-tiles (64 cols). Thread: ti=tid>>6 owns
// 4 rows, c=tid&63 owns one col. x_emb tile staged in LDS.
__global__ __launch_bounds__(256) void glgemm_kernel(
    const float* __restrict__ xemb, const float* __restrict__ gl_w,
    const float* __restrict__ gl_b, float* __restrict__ out_mean,
    float* __restrict__ out_scale) {
  const int ct = blockIdx.x & 15, it = blockIdx.x >> 4;
  const int tid = threadIdx.x;
  const int i0 = it * 16, col = ct * 64 + (tid & 63), ti = tid >> 6;
  __shared__ float xe[16][LAT];   // 16KB
  for (int o = tid; o < 16 * LAT; o += 256) {
    xe[o >> 8][o & 255] = xemb[(i0 + (o >> 8)) * LAT + (o & 255)];
  }
  __syncthreads();
  const float bias = gl_b[col];
  float acc0 = bias, acc1 = bias, acc2 = bias, acc3 = bias;
  const int r0 = ti * 4;
  #pragma unroll 4
  for (int k = 0; k < LAT; k++) {
    float w = gl_w[k * 1024 + col];
    acc0 += xe[r0 + 0][k] * w;
    acc1 += xe[r0 + 1][k] * w;
    acc2 += xe[r0 + 2][k] * w;
    acc3 += xe[r0 + 3][k] * w;
  }
  float accs[4] = {acc0, acc1, acc2, acc3};
  if (col < 512) {
    #pragma unroll
    for (int q = 0; q < 4; q++) out_mean[(i0 + r0 + q) * NN + col] = accs[q];
  } else {
    #pragma unroll
    for (int q = 0; q < 4; q++) {
      float lv = fminf(fmaxf(accs[q], -5.0f), 2.0f);
      out_scale[(i0 + r0 + q) * NN + (col - 512)] = expf(0.5f * lv);
    }
  }
}

extern "C" void kernel_launch(void* const* d_in, const int* in_sizes, int n_in,
                              void* d_out, int out_size, void* d_ws, size_t ws_size,
                              hipStream_t stream) {
  (void)in_sizes; (void)n_in; (void)out_size; (void)ws_size;
  const float* X        = (const float*)d_in[0];
  const float* Z        = (const float*)d_in[1];
  const float* es_now   = (const float*)d_in[2];
  const float* es_lag   = (const float*)d_in[3];
  const float* prior    = (const float*)d_in[4];
  const float* wp1      = (const float*)d_in[5];
  const float* bp1      = (const float*)d_in[6];
  const float* enc_in_w = (const float*)d_in[7];
  const float* enc_in_b = (const float*)d_in[8];
  const float* enc_out_w= (const float*)d_in[9];
  const float* enc_out_b= (const float*)d_in[10];
  const float* enc_l1_w = (const float*)d_in[11];
  const float* enc_l1_b = (const float*)d_in[12];
  const float* enc_l2_w = (const float*)d_in[13];
  const float* enc_l2_b = (const float*)d_in[14];
  const float* enc_g1   = (const float*)d_in[15];
  const float* enc_b1   = (const float*)d_in[16];
  const float* enc_g2   = (const float*)d_in[17];
  const float* enc_b2   = (const float*)d_in[18];
  const float* wp2      = (const float*)d_in[19];
  const float* bp2      = (const float*)d_in[20];
  const float* fs_w     = (const float*)d_in[21];
  const float* fs_b     = (const float*)d_in[22];
  const float* ft_w     = (const float*)d_in[23];
  const float* ft_b     = (const float*)d_in[24];
  const float* gru_w_ih = (const float*)d_in[25];
  const float* gru_w_hh = (const float*)d_in[26];
  const float* gru_b_ih = (const float*)d_in[27];
  const float* gru_b_hh = (const float*)d_in[28];
  const float* tp_w     = (const float*)d_in[29];
  const float* tp_b     = (const float*)d_in[30];
  const float* ltn_w    = (const float*)d_in[31];
  const float* ltn_b    = (const float*)d_in[32];
  const float* gat_wl   = (const float*)d_in[33];
  const float* gat_bl   = (const float*)d_in[34];
  const float* gat_wr   = (const float*)d_in[35];
  const float* gat_br   = (const float*)d_in[36];
  const float* gat_att  = (const float*)d_in[37];
  const float* gat_bias = (const float*)d_in[38];
  const float* gl_w     = (const float*)d_in[39];
  const float* gl_b     = (const float*)d_in[40];
  const int*   tctx     = (const int*)d_in[41];

  float* out = (float*)d_out;
  float* ws  = (float*)d_ws;
  // ws layout (floats)
  float* x_inst   = ws;                // 64*512
  float* x_lag    = ws + 32768;        // 64*512
  float* z2p      = ws + 65536;        // 512*128
  float* z2f      = ws + 131072;       // 512*128
  float* xl       = ws + 196608;       // 512*256
  float* xr       = ws + 327680;       // 512*256
  float* gi_table = ws + 458752;       // 100*384
  float* xemb     = ws + 497152;       // 512*256

  gitab_kernel<<<dim3(100), dim3(384), 0, stream>>>(gru_w_ih, gru_b_ih, gi_table);
  flow_kernel<<<dim3(NN), dim3(128), 0, stream>>>(Z, fs_w, fs_b, ft_w, ft_b, z2p);
  enc_kernel<<<dim3(BAT), dim3(256), 0, stream>>>(
      X, wp1, bp1, enc_in_w, enc_in_b, enc_out_w, enc_out_b,
      enc_l1_w, enc_l1_b, enc_l2_w, enc_l2_b,
      enc_g1, enc_b1, enc_g2, enc_b2, wp2, bp2, x_inst, x_lag);
  adj_kernel<<<dim3(2 * NN), dim3(256), 0, stream>>>(
      x_inst, x_lag, es_now, es_lag, prior, out);
  gru_kernel2<<<dim3(NN), dim3(384), 0, stream>>>(
      tctx, gru_w_hh, gru_b_hh, gi_table, tp_w, tp_b, z2p, z2f);
  zn_kernel<<<dim3(NN), dim3(256), 0, stream>>>(
      Z, z2f, ltn_w, ltn_b, gat_wl, gat_bl, gat_wr, gat_br, xl, xr);
  gat_kernel2<<<dim3(NN), dim3(256), 0, stream>>>(
      xl, xr, gat_att, gat_bias, xemb);
  glgemm_kernel<<<dim3(512), dim3(256), 0, stream>>>(
      xemb, gl_w, gl_b, out + 2 * NN * NN, out + 3 * NN * NN);
}